// Round 18
// baseline (109.631 us; speedup 1.0000x reference)
//
#include <hip/hip_runtime.h>
#include <hip/hip_fp16.h>
#include <math.h>

// Problem constants (fixed by reference setup_inputs)
#define BB 4096
#define LL 16
#define DD 512

// Marginal lookup table: 16 latents x NPTS points over [XMIN, XMIN+XRANGE]
#define NPTS   1024
#define XMIN   -6.0f
#define XRANGE 12.0f

#define LOG2E_F  1.4426950408889634f
#define LN2_F    0.6931471805599453f
#define LOG2PI_F 1.8378770664093453f

// Schraudolph f32 exp2: w = 2^23*(lp2 + BIASF); cvt_u32 saturates negatives
// to 0; bits reinterpreted as f32 ~ 2^lp2. Same numerics class as the
// R0-R13 marginal path (passed absmax 0.0).
#define SCALE23  8388608.0f
#define BIASF    126.94269504f

#if __has_builtin(__builtin_amdgcn_exp2f)
#define EXP2(x) __builtin_amdgcn_exp2f(x)
#else
#define EXP2(x) exp2f(x)
#endif
#if __has_builtin(__builtin_amdgcn_logf)
#define LOG2(x) __builtin_amdgcn_logf(x)
#else
#define LOG2(x) log2f(x)
#endif

typedef short bf16x8 __attribute__((ext_vector_type(8)));
typedef unsigned short u16x8 __attribute__((ext_vector_type(8)));
typedef float f32x16 __attribute__((ext_vector_type(16)));

// ws float-offset layout:
//   Wm  [0      , 262144)   bf16 FRAGMENT-MAJOR coef matrix (1 MB)
//   Fm  [262144 , 524288)   bf16 FRAGMENT-MAJOR feature matrix (1 MB)
//   ct  [524288 , 720896)   raw coefs transposed [part 3][l 16][j 4096]
//   rp  [720896 , 722944)   2048 recon block partials (pre-scaled)
//   klp [722944 , 723200)   256 KL block partials (pre-scaled)
//   tp  [723200 , 2820352)  table partials [jc 128][l 16][g 1024] (8 MB)
//   tab [2820352, 2836736)  marginal table [l 16][g 1024]
//   jp  [2836736, 2967808)  joint partials [chunk 32][i 4096]
#define WM_F   0
#define FM_F   262144
#define CT_F   524288
#define RP_F   720896
#define KLP_F  722944
#define TP_F   723200
#define TAB_F  2820352
#define JP_F   2836736

// Split x into bf16 hi (truncate) + bf16 lo (RNE of residual).
__device__ __forceinline__ void split_bf16(float x, unsigned short& h,
                                           unsigned short& l) {
  unsigned u = __float_as_uint(x);
  h = (unsigned short)(u >> 16);
  float hf = __uint_as_float((unsigned)h << 16);
  unsigned v = __float_as_uint(x - hf);
  unsigned r = v + 0x7FFFu + ((v >> 16) & 1u);
  l = (unsigned short)(r >> 16);
}

// Block-level sum reduction; result valid on thread 0. Re-entrant.
__device__ __forceinline__ float block_reduce(float v) {
  __shared__ float sm[4];
  __syncthreads();
#pragma unroll
  for (int off = 32; off; off >>= 1) v += __shfl_xor(v, off);
  if ((threadIdx.x & 63) == 0) sm[threadIdx.x >> 6] = v;
  __syncthreads();
  if (threadIdx.x == 0) v = (sm[0] + sm[1]) + (sm[2] + sm[3]);
  return v;
}

// ---------------------------------------------------------------------------
// Kernel A: recon partials + KL + out zero + W/F split-bf16 matrices + ct.
// lp2(i,j) = W_j . f_i, per-latent 8 K-slots: W=[Ah,Ah,Al,Bh,Bh,Bl,Ch,Cl],
// f=[x2h,x2l,x2h,xh,xl,xh,1,1] (dropped lo*lo ~2^-16 relative).
// FRAGMENT-MAJOR store (R17's win, -13.7us): wave-fragments contiguous,
//   slot = (tile*8 + s)*64 + half*32 + row32; 1KB coalesced wave loads.
// ---------------------------------------------------------------------------
__global__ __launch_bounds__(256) void prep_recon_kernel(
    const float4* __restrict__ data4, const float4* __restrict__ recon4,
    const float* __restrict__ zm, const float* __restrict__ zlv,
    const float* __restrict__ z,
    unsigned short* __restrict__ Wm, unsigned short* __restrict__ Fm,
    float* __restrict__ ct, float* __restrict__ rp,
    float* __restrict__ klp, float* __restrict__ out) {
  const int tid = threadIdx.x;
  const int b = blockIdx.x;

  if (b == 1024 && tid == 0) out[0] = 0.0f;  // consumed by final_kernel later

  {
    const int n4 = (BB * DD) / 4;
    int stride = gridDim.x * 256;
    float s = 0.0f;
    for (int k = b * 256 + tid; k < n4; k += stride) {
      float4 a = data4[k];
      float4 r = recon4[k];
      s += (fabsf(a.x - r.x) + fabsf(a.y - r.y)) +
           (fabsf(a.z - r.z) + fabsf(a.w - r.w));
    }
    float t = block_reduce(s);
    if (tid == 0) rp[b] = t * (1.0f / (float)(BB * DD));
  }

  if (b < 256) {  // coefs: W fragments + ct + KL
    int idx = b * 256 + tid;
    int j = idx >> 4;
    int l = idx & 15;
    float m = zm[idx];
    float lv = zlv[idx];
    float inv = EXP2(-lv * LOG2E_F);           // e^{-lv}
    float a = -0.5f * LOG2E_F * inv;           // log2-domain quadratic coef
    float c2 = -0.5f * LOG2E_F * (lv + LOG2PI_F);
    float braw = -2.0f * a * m;
    float craw = fmaf(a, m * m, c2);

    unsigned short Ah, Al, Bh, Bl, Ch, Cl;
    split_bf16(a, Ah, Al);
    split_bf16(braw, Bh, Bl);
    split_bf16(craw, Ch, Cl);
    u16x8 wv8 = {Ah, Ah, Al, Bh, Bh, Bl, Ch, Cl};
    size_t slot = ((size_t)(j >> 5) * 8 + (l >> 1)) * 64 + (l & 1) * 32 + (j & 31);
    *(u16x8*)(Wm + slot * 8) = wv8;

    ct[(0 * 16 + l) * 4096 + j] = a;
    ct[(1 * 16 + l) * 4096 + j] = braw;
    ct[(2 * 16 + l) * 4096 + j] = craw;

    float kls = m * m + EXP2(lv * LOG2E_F) - lv - 1.0f;
    float s = block_reduce(kls);
    if (tid == 0) klp[b] = s * (0.5f / (float)BB);
  } else if (b < 512) {  // features: F fragments from z
    int idx = (b - 256) * 256 + tid;
    int i = idx >> 4;
    int l = idx & 15;
    float x = z[idx];
    float x2 = x * x;
    unsigned short x2h, x2l, xh, xl;
    split_bf16(x2, x2h, x2l);
    split_bf16(x, xh, xl);
    u16x8 fv8 = {x2h, x2l, x2h, xh, xl, xh, 0x3F80, 0x3F80};  // 0x3F80=bf16 1.0
    size_t slot = ((size_t)(i >> 5) * 8 + (l >> 1)) * 64 + (l & 1) * 32 + (i & 31);
    *(u16x8*)(Fm + slot * 8) = fv8;
  }
}

// ---------------------------------------------------------------------------
// Kernel B1: marginal table build — Schraudolph, 4x parallelism.
// R17 analysis: exact v_exp_f32 (67M transcendentals at 1/4 rate) + a
// 128-iteration serial j-loop made build the largest controllable chunk.
// Fix: (a) Schraudolph exp2 (prescale coefs by 2^23 at LDS-stage, fold bias
// into c) -> body is 2 fma + cvt_u32 + add, no transcendental; (b) grid
// (128,16)=2048 blocks, 32 j per block -> serial depth 128 -> 32 iters.
// Numerics class == R0-R13's passing marginal path (coarser f16 variant).
// ---------------------------------------------------------------------------
__global__ __launch_bounds__(256) void table_build(
    const float* __restrict__ ct, float* __restrict__ tpart) {
  __shared__ float la[32], lb[32], lc[32];
  const int tid = threadIdx.x;
  const int jc = blockIdx.x;   // 0..127
  const int l  = blockIdx.y;   // 0..15
  const int j0 = jc * 32;
  if (tid < 32) {
    la[tid] = ct[(0 * 16 + l) * 4096 + j0 + tid] * SCALE23;
    lb[tid] = ct[(1 * 16 + l) * 4096 + j0 + tid] * SCALE23;
    lc[tid] = fmaf(ct[(2 * 16 + l) * 4096 + j0 + tid], SCALE23,
                   SCALE23 * BIASF);
  }
  const float H = XRANGE / (float)(NPTS - 1);
  float x[4], acc[4];
#pragma unroll
  for (int k = 0; k < 4; ++k) {
    x[k] = XMIN + (float)(k * 256 + tid) * H;
    acc[k] = 0.0f;
  }
  __syncthreads();
#pragma unroll 4
  for (int j = 0; j < 32; ++j) {
    float a = la[j], bb = lb[j], c = lc[j];  // wave-uniform LDS broadcast
#pragma unroll
    for (int k = 0; k < 4; ++k) {
      float w = fmaf(fmaf(a, x[k], bb), x[k], c);  // 2^23*(lp2+BIASF)
      unsigned u;
      asm("v_cvt_u32_f32 %0, %1" : "=v"(u) : "v"(w));  // neg saturates to 0
      acc[k] += __uint_as_float(u);
    }
  }
  float* o = tpart + ((size_t)jc * 16 + l) * NPTS;
#pragma unroll
  for (int k = 0; k < 4; ++k) o[k * 256 + tid] = acc[k];
}

// ---------------------------------------------------------------------------
// Kernel B2: sum the 128 jc-partials -> table[l][g]. grid 64 blocks.
// ---------------------------------------------------------------------------
__global__ __launch_bounds__(256) void table_reduce(
    const float* __restrict__ tpart, float* __restrict__ table) {
  const int e = blockIdx.x * 256 + threadIdx.x;
  float s0 = 0.0f, s1 = 0.0f, s2 = 0.0f, s3 = 0.0f;
  for (int jc = 0; jc < 128; jc += 4) {
    s0 += tpart[(size_t)(jc + 0) * (16 * NPTS) + e];
    s1 += tpart[(size_t)(jc + 1) * (16 * NPTS) + e];
    s2 += tpart[(size_t)(jc + 2) * (16 * NPTS) + e];
    s3 += tpart[(size_t)(jc + 3) * (16 * NPTS) + e];
  }
  table[e] = (s0 + s1) + (s2 + s3);
}

// ---------------------------------------------------------------------------
// Kernel C: MFMA joint, fragment-major coalesced loads (R17-verified).
// ---------------------------------------------------------------------------
__global__ __launch_bounds__(256, 4) void mfma_joint(
    const unsigned short* __restrict__ Wm,
    const unsigned short* __restrict__ Fm, float* __restrict__ jp) {
  const int tid = threadIdx.x;
  const int lane = tid & 63;
  const int wv = tid >> 6;
  const int it = blockIdx.x * 4 + wv;          // this wave's 32-i tile
  const int i0 = it * 32;
  const int jt0 = blockIdx.y * 4;              // 4 j-tiles (128 j's)
  const int r32 = lane & 31;

  // Preload B-frags (this wave's i-features, full K): 8 coalesced 1KB loads.
  bf16x8 bfr[8];
#pragma unroll
  for (int s = 0; s < 8; ++s)
    bfr[s] = *(const bf16x8*)(Fm + (((size_t)it * 8 + s) * 64 + lane) * 8);
#pragma unroll
  for (int s = 0; s < 8; ++s) asm volatile("" : "+v"(bfr[s]));

  const float KK = SCALE23 * BIASF;
  float accJ = 0.0f;

#pragma unroll
  for (int t = 0; t < 4; ++t) {
    const int jt = jt0 + t;
    f32x16 acc;
#pragma unroll
    for (int e = 0; e < 16; ++e) acc[e] = 0.0f;
#pragma unroll
    for (int s = 0; s < 8; ++s) {
      bf16x8 af =
          *(const bf16x8*)(Wm + (((size_t)jt * 8 + s) * 64 + lane) * 8);
      acc = __builtin_amdgcn_mfma_f32_32x32x16_bf16(af, bfr[s], acc, 0, 0, 0);
    }
    // Epilogue: lane holds 16 j-rows of col i -> Schraudolph exp2 + sum.
#pragma unroll
    for (int e = 0; e < 16; ++e) {
      float w = fmaf(acc[e], SCALE23, KK);     // 2^23*(lp2sum + BIASF)
      unsigned u;
      asm("v_cvt_u32_f32 %0, %1" : "=v"(u) : "v"(w));  // neg saturates to 0
      accJ += __uint_as_float(u);
    }
  }

  accJ += __shfl_xor(accJ, 32);  // merge the two row-halves of this col
  if (lane < 32)
    jp[(size_t)blockIdx.y * BB + (size_t)(i0 + r32)] = accJ;  // coalesced
}

// ---------------------------------------------------------------------------
// Kernel D: final. Sum 32 joint chunks per i, LDS-staged table interpolation
// for the 16 marginals, logs, fold recon/KL into out[0].
// ---------------------------------------------------------------------------
__global__ __launch_bounds__(256) void final_kernel(
    const float* __restrict__ z, const float* __restrict__ jp,
    const float* __restrict__ table, const float* __restrict__ rp,
    const float* __restrict__ klp, float* __restrict__ out) {
  __shared__ float ltab[16 * NPTS];  // 64 KB
  const int tid = threadIdx.x;
  const int i = blockIdx.x * 256 + tid;

  for (int t = tid; t < 16 * NPTS; t += 256) ltab[t] = table[t];

  float s0 = 0.0f, s1 = 0.0f, s2 = 0.0f, s3 = 0.0f;
#pragma unroll 8
  for (int c = 0; c < 32; c += 4) {
    s0 += jp[(size_t)(c + 0) * BB + i];
    s1 += jp[(size_t)(c + 1) * BB + i];
    s2 += jp[(size_t)(c + 2) * BB + i];
    s3 += jp[(size_t)(c + 3) * BB + i];
  }
  float lg = LOG2((s0 + s1) + (s2 + s3));  // log2 S_joint

  __syncthreads();  // table staged

  const float4* zp = (const float4*)(z + (size_t)i * 16);
  const float SC = (float)(NPTS - 1) / XRANGE;
#pragma unroll
  for (int q = 0; q < 4; ++q) {
    float4 v = zp[q];
    float xs[4] = {v.x, v.y, v.z, v.w};
#pragma unroll
    for (int k = 0; k < 4; ++k) {
      int l = 4 * q + k;
      float t = (xs[k] - XMIN) * SC;
      t = fminf(fmaxf(t, 0.0f), (float)(NPTS - 2) + 0.999f);
      int g = (int)t;
      float f = t - (float)g;
      float m0 = ltab[l * NPTS + g];
      float m1 = ltab[l * NPTS + g + 1];
      lg -= LOG2(fmaf(f, m1 - m0, m0));
    }
  }

  float tval = lg * (LN2_F / (float)BB);
  if (blockIdx.x == 0) {
#pragma unroll
    for (int q = 0; q < 8; ++q) tval += rp[tid + 256 * q];
    tval += klp[tid];
  }

  __syncthreads();  // all gathers done; safe to reuse ltab
#pragma unroll
  for (int off = 32; off; off >>= 1) tval += __shfl_xor(tval, off);
  if ((tid & 63) == 0) ltab[tid >> 6] = tval;
  __syncthreads();
  if (tid == 0) atomicAdd(out, (ltab[0] + ltab[1]) + (ltab[2] + ltab[3]));
}

extern "C" void kernel_launch(void* const* d_in, const int* in_sizes, int n_in,
                              void* d_out, int out_size, void* d_ws, size_t ws_size,
                              hipStream_t stream) {
  const float* data  = (const float*)d_in[0];
  const float* recon = (const float*)d_in[1];
  const float* z     = (const float*)d_in[2];
  const float* zm    = (const float*)d_in[3];
  const float* zlv   = (const float*)d_in[4];
  float* out = (float*)d_out;
  float* ws  = (float*)d_ws;

  unsigned short* Wm = (unsigned short*)(ws + WM_F);
  unsigned short* Fm = (unsigned short*)(ws + FM_F);
  float* ct  = ws + CT_F;
  float* rp  = ws + RP_F;
  float* klp = ws + KLP_F;
  float* tp  = ws + TP_F;
  float* tab = ws + TAB_F;
  float* jp  = ws + JP_F;

  hipLaunchKernelGGL(prep_recon_kernel, dim3(2048), dim3(256), 0, stream,
                     reinterpret_cast<const float4*>(data),
                     reinterpret_cast<const float4*>(recon),
                     zm, zlv, z, Wm, Fm, ct, rp, klp, out);
  hipLaunchKernelGGL(table_build, dim3(128, 16), dim3(256), 0, stream,
                     ct, tp);
  hipLaunchKernelGGL(table_reduce, dim3((16 * NPTS) / 256), dim3(256), 0,
                     stream, tp, tab);
  hipLaunchKernelGGL(mfma_joint, dim3(32, 32), dim3(256), 0, stream,
                     Wm, Fm, jp);
  hipLaunchKernelGGL(final_kernel, dim3(BB / 256), dim3(256), 0, stream,
                     z, jp, tab, rp, klp, out);
}

// Round 19
// 101.354 us; speedup vs baseline: 1.0817x; 1.0817x over previous
//
#include <hip/hip_runtime.h>
#include <hip/hip_fp16.h>
#include <math.h>

// Problem constants (fixed by reference setup_inputs)
#define BB 4096
#define LL 16
#define DD 512

// Marginal lookup table: 16 latents x NPTS points over [XMIN, XMIN+XRANGE]
#define NPTS   1024
#define XMIN   -6.0f
#define XRANGE 12.0f

#define LOG2E_F  1.4426950408889634f
#define LN2_F    0.6931471805599453f
#define LOG2PI_F 1.8378770664093453f

// Schraudolph f32 exp2 for the joint: w = 2^23*(lp2sum + BIASF); cvt_u32
// saturates negatives to 0; bits reinterpreted as f32 ~ 2^lp2sum.
#define SCALE23  8388608.0f
#define BIASF    126.94269504f

#if __has_builtin(__builtin_amdgcn_exp2f)
#define EXP2(x) __builtin_amdgcn_exp2f(x)
#else
#define EXP2(x) exp2f(x)
#endif
#if __has_builtin(__builtin_amdgcn_logf)
#define LOG2(x) __builtin_amdgcn_logf(x)
#else
#define LOG2(x) log2f(x)
#endif

typedef short bf16x8 __attribute__((ext_vector_type(8)));
typedef unsigned short u16x8 __attribute__((ext_vector_type(8)));
typedef float f32x16 __attribute__((ext_vector_type(16)));

// ws float-offset layout:
//   Wm  [0      , 262144)   bf16 FRAGMENT-MAJOR coef matrix (1 MB):
//                           slot[(jt*8+s)*64 + half*32 + (j&31)] of u16x8
//   Fm  [262144 , 524288)   bf16 FRAGMENT-MAJOR feature matrix (1 MB), same
//   ct  [524288 , 720896)   raw coefs transposed [part 3][l 16][j 4096]
//   rp  [720896 , 722944)   2048 recon block partials (pre-scaled)
//   klp [722944 , 723200)   256 KL block partials (pre-scaled)
//   tp  [723200 , 1247488)  table partials [jc 32][l 16][g 1024]
//   tab [1247488, 1263872)  marginal table [l 16][g 1024]
//   jp  [1263872, 1394944)  joint partials [chunk 32][i 4096]
#define WM_F   0
#define FM_F   262144
#define CT_F   524288
#define RP_F   720896
#define KLP_F  722944
#define TP_F   723200
#define TAB_F  1247488
#define JP_F   1263872

// Split x into bf16 hi (truncate) + bf16 lo (RNE of residual).
__device__ __forceinline__ void split_bf16(float x, unsigned short& h,
                                           unsigned short& l) {
  unsigned u = __float_as_uint(x);
  h = (unsigned short)(u >> 16);
  float hf = __uint_as_float((unsigned)h << 16);
  unsigned v = __float_as_uint(x - hf);
  unsigned r = v + 0x7FFFu + ((v >> 16) & 1u);
  l = (unsigned short)(r >> 16);
}

// Block-level sum reduction; result valid on thread 0. Re-entrant.
__device__ __forceinline__ float block_reduce(float v) {
  __shared__ float sm[4];
  __syncthreads();
#pragma unroll
  for (int off = 32; off; off >>= 1) v += __shfl_xor(v, off);
  if ((threadIdx.x & 63) == 0) sm[threadIdx.x >> 6] = v;
  __syncthreads();
  if (threadIdx.x == 0) v = (sm[0] + sm[1]) + (sm[2] + sm[3]);
  return v;
}

// ---------------------------------------------------------------------------
// Kernel A: recon partials + KL + out zero + W/F split-bf16 matrices + ct.
// lp2(i,j) = W_j . f_i, per-latent 8 K-slots: W=[Ah,Ah,Al,Bh,Bh,Bl,Ch,Cl],
// f=[x2h,x2l,x2h,xh,xl,xh,1,1] (dropped lo*lo ~2^-16 relative).
// FRAGMENT-MAJOR store (R17's win, -13.7us vs row-major: wave loads were
// touching 32 cache lines each; now contiguous 1KB transactions):
//   slot = (tile*8 + s)*64 + half*32 + row32; from (j,l): s=l>>1, half=l&1.
// ---------------------------------------------------------------------------
__global__ __launch_bounds__(256) void prep_recon_kernel(
    const float4* __restrict__ data4, const float4* __restrict__ recon4,
    const float* __restrict__ zm, const float* __restrict__ zlv,
    const float* __restrict__ z,
    unsigned short* __restrict__ Wm, unsigned short* __restrict__ Fm,
    float* __restrict__ ct, float* __restrict__ rp,
    float* __restrict__ klp, float* __restrict__ out) {
  const int tid = threadIdx.x;
  const int b = blockIdx.x;

  if (b == 1024 && tid == 0) out[0] = 0.0f;  // consumed by final_kernel later

  {
    const int n4 = (BB * DD) / 4;
    int stride = gridDim.x * 256;
    float s = 0.0f;
    for (int k = b * 256 + tid; k < n4; k += stride) {
      float4 a = data4[k];
      float4 r = recon4[k];
      s += (fabsf(a.x - r.x) + fabsf(a.y - r.y)) +
           (fabsf(a.z - r.z) + fabsf(a.w - r.w));
    }
    float t = block_reduce(s);
    if (tid == 0) rp[b] = t * (1.0f / (float)(BB * DD));
  }

  if (b < 256) {  // coefs: W fragments + ct + KL
    int idx = b * 256 + tid;
    int j = idx >> 4;
    int l = idx & 15;
    float m = zm[idx];
    float lv = zlv[idx];
    float inv = EXP2(-lv * LOG2E_F);           // e^{-lv}
    float a = -0.5f * LOG2E_F * inv;           // log2-domain quadratic coef
    float c2 = -0.5f * LOG2E_F * (lv + LOG2PI_F);
    float braw = -2.0f * a * m;
    float craw = fmaf(a, m * m, c2);

    unsigned short Ah, Al, Bh, Bl, Ch, Cl;
    split_bf16(a, Ah, Al);
    split_bf16(braw, Bh, Bl);
    split_bf16(craw, Ch, Cl);
    u16x8 wv8 = {Ah, Ah, Al, Bh, Bh, Bl, Ch, Cl};
    size_t slot = ((size_t)(j >> 5) * 8 + (l >> 1)) * 64 + (l & 1) * 32 + (j & 31);
    *(u16x8*)(Wm + slot * 8) = wv8;

    ct[(0 * 16 + l) * 4096 + j] = a;
    ct[(1 * 16 + l) * 4096 + j] = braw;
    ct[(2 * 16 + l) * 4096 + j] = craw;

    float kls = m * m + EXP2(lv * LOG2E_F) - lv - 1.0f;
    float s = block_reduce(kls);
    if (tid == 0) klp[b] = s * (0.5f / (float)BB);
  } else if (b < 512) {  // features: F fragments from z
    int idx = (b - 256) * 256 + tid;
    int i = idx >> 4;
    int l = idx & 15;
    float x = z[idx];
    float x2 = x * x;
    unsigned short x2h, x2l, xh, xl;
    split_bf16(x2, x2h, x2l);
    split_bf16(x, xh, xl);
    u16x8 fv8 = {x2h, x2l, x2h, xh, xl, xh, 0x3F80, 0x3F80};  // 0x3F80=bf16 1.0
    size_t slot = ((size_t)(i >> 5) * 8 + (l >> 1)) * 64 + (l & 1) * 32 + (i & 31);
    *(u16x8*)(Fm + slot * 8) = fv8;
  }
}

// ---------------------------------------------------------------------------
// Kernel B1: marginal table build (exact v_exp_f32). grid (32 jc, 16 l).
// R18 lesson: the Schraudolph + 4x-grid variant REGRESSED total by ~9us
// (outside noise); this exact-exp version is part of the verified-best
// (100.7us) configuration. Do not "optimize" without within-probe A/B.
// ---------------------------------------------------------------------------
__global__ __launch_bounds__(256) void table_build(
    const float* __restrict__ ct, float* __restrict__ tpart) {
  __shared__ float la[128], lb[128], lc[128];
  const int tid = threadIdx.x;
  const int jc = blockIdx.x;
  const int l  = blockIdx.y;
  const int j0 = jc * 128;
  if (tid < 128) {
    la[tid] = ct[(0 * 16 + l) * 4096 + j0 + tid];
    lb[tid] = ct[(1 * 16 + l) * 4096 + j0 + tid];
    lc[tid] = ct[(2 * 16 + l) * 4096 + j0 + tid];
  }
  const float H = XRANGE / (float)(NPTS - 1);
  float x[4], acc[4];
#pragma unroll
  for (int k = 0; k < 4; ++k) {
    x[k] = XMIN + (float)(k * 256 + tid) * H;
    acc[k] = 0.0f;
  }
  __syncthreads();
#pragma unroll 2
  for (int j = 0; j < 128; ++j) {
    float a = la[j], bb = lb[j], c = lc[j];
#pragma unroll
    for (int k = 0; k < 4; ++k) {
      float lp = fmaf(fmaf(a, x[k], bb), x[k], c);
      acc[k] += EXP2(lp);
    }
  }
  float* o = tpart + ((size_t)jc * 16 + l) * NPTS;
#pragma unroll
  for (int k = 0; k < 4; ++k) o[k * 256 + tid] = acc[k];
}

// ---------------------------------------------------------------------------
// Kernel B2: sum the 32 jc-partials -> table[l][g]. grid 64 blocks.
// ---------------------------------------------------------------------------
__global__ __launch_bounds__(256) void table_reduce(
    const float* __restrict__ tpart, float* __restrict__ table) {
  const int e = blockIdx.x * 256 + threadIdx.x;
  float s = 0.0f;
#pragma unroll 4
  for (int jc = 0; jc < 32; ++jc) s += tpart[(size_t)jc * (16 * NPTS) + e];
  table[e] = s;
}

// ---------------------------------------------------------------------------
// Kernel C: MFMA joint, fragment-major coalesced loads.
// Per wave: one 32-i tile, 4 j-tiles; 8 K-step mfma_f32_32x32x16_bf16 chain
// per tile; Schraudolph exp2 epilogue summed over j per i (D col=lane&31=i,
// verified by R16/R17 absmax=0). All fragment loads are contiguous 1KB
// wave transactions.
// ---------------------------------------------------------------------------
__global__ __launch_bounds__(256, 4) void mfma_joint(
    const unsigned short* __restrict__ Wm,
    const unsigned short* __restrict__ Fm, float* __restrict__ jp) {
  const int tid = threadIdx.x;
  const int lane = tid & 63;
  const int wv = tid >> 6;
  const int it = blockIdx.x * 4 + wv;          // this wave's 32-i tile
  const int i0 = it * 32;
  const int jt0 = blockIdx.y * 4;              // 4 j-tiles (128 j's)
  const int r32 = lane & 31;

  // Preload B-frags (this wave's i-features, full K): 8 coalesced 1KB loads.
  bf16x8 bfr[8];
#pragma unroll
  for (int s = 0; s < 8; ++s)
    bfr[s] = *(const bf16x8*)(Fm + (((size_t)it * 8 + s) * 64 + lane) * 8);
#pragma unroll
  for (int s = 0; s < 8; ++s) asm volatile("" : "+v"(bfr[s]));

  const float KK = SCALE23 * BIASF;
  float accJ = 0.0f;

#pragma unroll
  for (int t = 0; t < 4; ++t) {
    const int jt = jt0 + t;
    f32x16 acc;
#pragma unroll
    for (int e = 0; e < 16; ++e) acc[e] = 0.0f;
#pragma unroll
    for (int s = 0; s < 8; ++s) {
      bf16x8 af =
          *(const bf16x8*)(Wm + (((size_t)jt * 8 + s) * 64 + lane) * 8);
      acc = __builtin_amdgcn_mfma_f32_32x32x16_bf16(af, bfr[s], acc, 0, 0, 0);
    }
    // Epilogue: lane holds 16 j-rows of col i -> Schraudolph exp2 + sum.
#pragma unroll
    for (int e = 0; e < 16; ++e) {
      float w = fmaf(acc[e], SCALE23, KK);     // 2^23*(lp2sum + BIASF)
      unsigned u;
      asm("v_cvt_u32_f32 %0, %1" : "=v"(u) : "v"(w));  // neg saturates to 0
      accJ += __uint_as_float(u);
    }
  }

  accJ += __shfl_xor(accJ, 32);  // merge the two row-halves of this col
  if (lane < 32)
    jp[(size_t)blockIdx.y * BB + (size_t)(i0 + r32)] = accJ;  // coalesced
}

// ---------------------------------------------------------------------------
// Kernel D: final. Sum 32 joint chunks per i, LDS-staged table interpolation
// for the 16 marginals, logs, fold recon/KL into out[0].
// ---------------------------------------------------------------------------
__global__ __launch_bounds__(256) void final_kernel(
    const float* __restrict__ z, const float* __restrict__ jp,
    const float* __restrict__ table, const float* __restrict__ rp,
    const float* __restrict__ klp, float* __restrict__ out) {
  __shared__ float ltab[16 * NPTS];  // 64 KB
  const int tid = threadIdx.x;
  const int i = blockIdx.x * 256 + tid;

  for (int t = tid; t < 16 * NPTS; t += 256) ltab[t] = table[t];

  float s0 = 0.0f, s1 = 0.0f, s2 = 0.0f, s3 = 0.0f;
#pragma unroll 8
  for (int c = 0; c < 32; c += 4) {
    s0 += jp[(size_t)(c + 0) * BB + i];
    s1 += jp[(size_t)(c + 1) * BB + i];
    s2 += jp[(size_t)(c + 2) * BB + i];
    s3 += jp[(size_t)(c + 3) * BB + i];
  }
  float lg = LOG2((s0 + s1) + (s2 + s3));  // log2 S_joint

  __syncthreads();  // table staged

  const float4* zp = (const float4*)(z + (size_t)i * 16);
  const float SC = (float)(NPTS - 1) / XRANGE;
#pragma unroll
  for (int q = 0; q < 4; ++q) {
    float4 v = zp[q];
    float xs[4] = {v.x, v.y, v.z, v.w};
#pragma unroll
    for (int k = 0; k < 4; ++k) {
      int l = 4 * q + k;
      float t = (xs[k] - XMIN) * SC;
      t = fminf(fmaxf(t, 0.0f), (float)(NPTS - 2) + 0.999f);
      int g = (int)t;
      float f = t - (float)g;
      float m0 = ltab[l * NPTS + g];
      float m1 = ltab[l * NPTS + g + 1];
      lg -= LOG2(fmaf(f, m1 - m0, m0));
    }
  }

  float tval = lg * (LN2_F / (float)BB);
  if (blockIdx.x == 0) {
#pragma unroll
    for (int q = 0; q < 8; ++q) tval += rp[tid + 256 * q];
    tval += klp[tid];
  }

  __syncthreads();  // all gathers done; safe to reuse ltab
#pragma unroll
  for (int off = 32; off; off >>= 1) tval += __shfl_xor(tval, off);
  if ((tid & 63) == 0) ltab[tid >> 6] = tval;
  __syncthreads();
  if (tid == 0) atomicAdd(out, (ltab[0] + ltab[1]) + (ltab[2] + ltab[3]));
}

extern "C" void kernel_launch(void* const* d_in, const int* in_sizes, int n_in,
                              void* d_out, int out_size, void* d_ws, size_t ws_size,
                              hipStream_t stream) {
  const float* data  = (const float*)d_in[0];
  const float* recon = (const float*)d_in[1];
  const float* z     = (const float*)d_in[2];
  const float* zm    = (const float*)d_in[3];
  const float* zlv   = (const float*)d_in[4];
  float* out = (float*)d_out;
  float* ws  = (float*)d_ws;

  unsigned short* Wm = (unsigned short*)(ws + WM_F);
  unsigned short* Fm = (unsigned short*)(ws + FM_F);
  float* ct  = ws + CT_F;
  float* rp  = ws + RP_F;
  float* klp = ws + KLP_F;
  float* tp  = ws + TP_F;
  float* tab = ws + TAB_F;
  float* jp  = ws + JP_F;

  hipLaunchKernelGGL(prep_recon_kernel, dim3(2048), dim3(256), 0, stream,
                     reinterpret_cast<const float4*>(data),
                     reinterpret_cast<const float4*>(recon),
                     zm, zlv, z, Wm, Fm, ct, rp, klp, out);
  hipLaunchKernelGGL(table_build, dim3(32, 16), dim3(256), 0, stream,
                     ct, tp);
  hipLaunchKernelGGL(table_reduce, dim3((16 * NPTS) / 256), dim3(256), 0,
                     stream, tp, tab);
  hipLaunchKernelGGL(mfma_joint, dim3(32, 32), dim3(256), 0, stream,
                     Wm, Fm, jp);
  hipLaunchKernelGGL(final_kernel, dim3(BB / 256), dim3(256), 0, stream,
                     z, jp, tab, rp, klp, out);
}